// Round 10
// baseline (1080.458 us; speedup 1.0000x reference)
//
#include <hip/hip_runtime.h>

#define NB   32
#define NN   100000
#define NE   1000000
#define HD   64
#define AD   5
#define NL   3
#define NRL  231      // N_REL + 1
#define NTM  365
#define NOUT 228096   // 32 * 7128
#define NBLK1 391     // ceil(NN/256)
#define NDBIN 1024    // degree bins for balance sort

// meta packing: w0 = src | (rel<<17) | (cls<<25) ; w1 = ta | (q<<9)

// bf16 helpers (hidden stored as bf16 to halve gather traffic)
__device__ __forceinline__ float bflo(unsigned u) { return __uint_as_float(u << 16); }
__device__ __forceinline__ float bfhi(unsigned u) { return __uint_as_float(u & 0xffff0000u); }
__device__ __forceinline__ unsigned packbf2(float x, float y) {
    unsigned ux = __float_as_uint(x), uy = __float_as_uint(y);
    ux = (ux + 0x7fffu + ((ux >> 16) & 1u)) >> 16;
    uy = (uy + 0x7fffu + ((uy >> 16) & 1u)) >> 16;
    return ux | (uy << 16);
}

// ---------------------------------------------------------------------------
// WT[c][k][h] = W_c[h][k], c: 0=Wf(pos) 1=Wn(zero) 2=Wp(neg)
__global__ __launch_bounds__(256) void prep_wt_kernel(
    const float* __restrict__ Wp, const float* __restrict__ Wn,
    const float* __restrict__ Wf, float* __restrict__ WT)
{
    int i = blockIdx.x * 256 + threadIdx.x;
    if (i >= 3 * 64 * 64) return;
    int c = i >> 12;
    int k = (i >> 6) & 63;
    int h = i & 63;
    const float* W = (c == 0) ? Wf : (c == 1 ? Wn : Wp);
    WT[i] = W[h * 64 + k];
}

// ---------------------------------------------------------------------------
__global__ __launch_bounds__(256) void prep_tables_kernel(
    const float* __restrict__ rela_embed,   // [3][231][64]
    const float* __restrict__ W1,           // [3][5][192]
    float* __restrict__ Trel,               // [3][231][8]
    float* __restrict__ Tq)                 // [3][231][8]
{
    int l = blockIdx.x;
    int r = threadIdx.x;
    if (r >= NRL) return;
    const float4* rrow = (const float4*)(rela_embed + ((size_t)l * NRL + r) * HD);
    const float* W1l = W1 + (size_t)l * AD * 192;
    float tr[AD] = {0,0,0,0,0}, tq[AD] = {0,0,0,0,0};
    #pragma unroll
    for (int k4 = 0; k4 < 16; ++k4) {
        float4 x = rrow[k4];
        #pragma unroll
        for (int a = 0; a < AD; ++a) {
            const float* wr = W1l + a * 192 + 64 + k4 * 4;
            const float* wq = W1l + a * 192 + 128 + k4 * 4;
            tr[a] = fmaf(x.x, wr[0], tr[a]); tr[a] = fmaf(x.y, wr[1], tr[a]);
            tr[a] = fmaf(x.z, wr[2], tr[a]); tr[a] = fmaf(x.w, wr[3], tr[a]);
            tq[a] = fmaf(x.x, wq[0], tq[a]); tq[a] = fmaf(x.y, wq[1], tq[a]);
            tq[a] = fmaf(x.z, wq[2], tq[a]); tq[a] = fmaf(x.w, wq[3], tq[a]);
        }
    }
    float* tro = Trel + ((size_t)l * NRL + r) * 8;
    float* tqo = Tq   + ((size_t)l * NRL + r) * 8;
    #pragma unroll
    for (int a = 0; a < AD; ++a) { tro[a] = tr[a]; tqo[a] = tq[a]; }
    tro[5] = tro[6] = tro[7] = 0.f;
    tqo[5] = tqo[6] = tqo[7] = 0.f;
}

// ---------------------------------------------------------------------------
// Counting sort by dst (dst-only: long segments keep MLP alive — R8 lesson)
__global__ __launch_bounds__(256) void hist_kernel(
    const int* __restrict__ dst_idx, int* __restrict__ deg)
{
    int e = blockIdx.x * 256 + threadIdx.x;
    if (e < NE) atomicAdd(&deg[dst_idx[e]], 1);
}

__global__ __launch_bounds__(256) void scan1_kernel(
    const int* __restrict__ deg, int* __restrict__ tmp, int* __restrict__ bsum)
{
    __shared__ int s[256];
    int tid = threadIdx.x;
    int i = blockIdx.x * 256 + tid;
    int v = (i < NN) ? deg[i] : 0;
    s[tid] = v;
    __syncthreads();
    #pragma unroll
    for (int st = 1; st < 256; st <<= 1) {
        int t = (tid >= st) ? s[tid - st] : 0;
        __syncthreads();
        s[tid] += t;
        __syncthreads();
    }
    if (i < NN) tmp[i] = s[tid];
    if (tid == 255) bsum[blockIdx.x] = s[255];
}

__global__ __launch_bounds__(512) void scan2_kernel(
    const int* __restrict__ bsum, int* __restrict__ bpref)
{
    __shared__ int s[512];
    int tid = threadIdx.x;
    int v = (tid < NBLK1) ? bsum[tid] : 0;
    s[tid] = v;
    __syncthreads();
    #pragma unroll
    for (int st = 1; st < 512; st <<= 1) {
        int t = (tid >= st) ? s[tid - st] : 0;
        __syncthreads();
        s[tid] += t;
        __syncthreads();
    }
    if (tid < NBLK1) bpref[tid] = s[tid] - v;  // exclusive
}

// finalize edge-sort offsets; also histogram node degrees for balance sort
__global__ __launch_bounds__(256) void scan3_kernel(
    const int* __restrict__ deg, const int* __restrict__ tmp,
    const int* __restrict__ bpref, int* __restrict__ off, int* __restrict__ cursor,
    int* __restrict__ dhist)
{
    int i = blockIdx.x * 256 + threadIdx.x;
    if (i >= NN) return;
    int d = deg[i];
    int incl = tmp[i] + bpref[i >> 8];
    off[i + 1] = incl;
    cursor[i] = incl - d;
    if (i == 0) off[0] = 0;
    int bin = (d < NDBIN) ? d : (NDBIN - 1);
    atomicAdd(&dhist[bin], 1);
}

// descending-degree cursor: dcur[b] = NN - inclusive_prefix(dhist, b)
__global__ __launch_bounds__(1024) void dscan_kernel(
    const int* __restrict__ dhist, int* __restrict__ dcur)
{
    __shared__ int s[NDBIN];
    int tid = threadIdx.x;
    int v = dhist[tid];
    s[tid] = v;
    __syncthreads();
    #pragma unroll
    for (int st = 1; st < NDBIN; st <<= 1) {
        int t = (tid >= st) ? s[tid - st] : 0;
        __syncthreads();
        s[tid] += t;
        __syncthreads();
    }
    dcur[tid] = NN - s[tid];   // start of bin tid in descending order
}

// perm[pos] = node, nodes sorted by descending degree
__global__ __launch_bounds__(256) void dscatter_kernel(
    const int* __restrict__ deg, int* __restrict__ dcur, int* __restrict__ perm)
{
    int n = blockIdx.x * 256 + threadIdx.x;
    if (n >= NN) return;
    int d = deg[n];
    int bin = (d < NDBIN) ? d : (NDBIN - 1);
    int pos = atomicAdd(&dcur[bin], 1);
    perm[pos] = n;
}

// scatter into dst-sorted order; also computes layer-0 score
// (proj-free: sigmoid(sum_a relu(Trel0+Tq0)*W2))
__global__ __launch_bounds__(256) void sort_scatter_kernel(
    const int* __restrict__ dst_idx, const int* __restrict__ src_idx,
    const int* __restrict__ rel_idx, const int* __restrict__ rel_time,
    const int* __restrict__ batch_idx, const int* __restrict__ query_rel,
    const float* __restrict__ Trel0, const float* __restrict__ Tq0,
    const float* __restrict__ W2,
    int* __restrict__ cursor, int2* __restrict__ meta,
    float* __restrict__ score0)
{
    int e = blockIdx.x * 256 + threadIdx.x;
    if (e >= NE) return;
    int d = dst_idx[e];
    int rt = rel_time[e];
    int cls = (rt > 0) ? 0 : ((rt == 0) ? 1 : 2);
    int ta = (rt < 0) ? -rt : rt;
    int rel = rel_idx[e];
    int q = query_rel[batch_idx[e]];
    int pos = atomicAdd(&cursor[d], 1);
    int2 m;
    m.x = src_idx[e] | (rel << 17) | (cls << 25);
    m.y = ta | (q << 9);
    meta[pos] = m;

    float4 t0 = *(const float4*)(Trel0 + rel * 8);
    float  t4 = Trel0[rel * 8 + 4];
    float4 u0 = *(const float4*)(Tq0 + q * 8);
    float  u4 = Tq0[q * 8 + 4];
    float z = 0.f;
    z = fmaf(fmaxf(t0.x + u0.x, 0.f), W2[0], z);
    z = fmaf(fmaxf(t0.y + u0.y, 0.f), W2[1], z);
    z = fmaf(fmaxf(t0.z + u0.z, 0.f), W2[2], z);
    z = fmaf(fmaxf(t0.w + u0.w, 0.f), W2[3], z);
    z = fmaf(fmaxf(t4   + u4,   0.f), W2[4], z);
    score0[pos] = 1.f / (1.f + __expf(-z));
}

// ---------------------------------------------------------------------------
// Standalone score for L1/L2 (64 edges/wave — R6 lesson).
__global__ __launch_bounds__(256) void score_kernel(
    const float* __restrict__ proj,     // [NN][8]
    const float* __restrict__ Trel,
    const float* __restrict__ Tq,
    const float* __restrict__ W2,
    const int2* __restrict__ meta,
    float* __restrict__ score)
{
    int j = blockIdx.x * 256 + threadIdx.x;
    if (j >= NE) return;
    int2 mt = meta[j];
    int rel = (mt.x >> 17) & 0xFF;
    int q   = (mt.y >> 9) & 0xFF;
    int src = mt.x & 0x1FFFF;

    float4 t0 = *(const float4*)(Trel + rel * 8);
    float  t4 = Trel[rel * 8 + 4];
    float4 u0 = *(const float4*)(Tq + q * 8);
    float  u4 = Tq[q * 8 + 4];
    float4 p0 = *(const float4*)(proj + (size_t)src * 8);
    float  p4 = proj[(size_t)src * 8 + 4];
    float z = 0.f;
    z = fmaf(fmaxf(p0.x + t0.x + u0.x, 0.f), W2[0], z);
    z = fmaf(fmaxf(p0.y + t0.y + u0.y, 0.f), W2[1], z);
    z = fmaf(fmaxf(p0.z + t0.z + u0.z, 0.f), W2[2], z);
    z = fmaf(fmaxf(p0.w + t0.w + u0.w, 0.f), W2[3], z);
    z = fmaf(fmaxf(p4   + t4   + u4,   0.f), W2[4], z);
    score[j] = 1.f / (1.f + __expf(-z));
}

// ---------------------------------------------------------------------------
// One edge, 8-lane group (lane covers h = hc*8..hc*8+7).
// A[6] = [cls0 lo, cls0 hi, cls1 lo, cls1 hi, cls2 lo, cls2 hi]
template <bool HZ>
__device__ __forceinline__ void edge1(
    int2 m, float sc, int hc8,
    const ushort* __restrict__ hidden_in,
    const float* __restrict__ rela, const float* __restrict__ temb,
    float4* __restrict__ A)
{
    int src = m.x & 0x1FFFF, rel = (m.x >> 17) & 0xFF;
    int cl  = (m.x >> 25) & 3, ta = m.y & 511;
    const float* rp = rela + rel * HD + hc8;
    const float* tp = temb + ta * HD + hc8;
    float4 rv0 = *(const float4*)rp;
    float4 rv1 = *(const float4*)(rp + 4);
    float4 tv0 = *(const float4*)tp;
    float4 tv1 = *(const float4*)(tp + 4);
    float4 v0, v1;
    v0.x = rv0.x + tv0.x; v0.y = rv0.y + tv0.y;
    v0.z = rv0.z + tv0.z; v0.w = rv0.w + tv0.w;
    v1.x = rv1.x + tv1.x; v1.y = rv1.y + tv1.y;
    v1.z = rv1.z + tv1.z; v1.w = rv1.w + tv1.w;
    if (!HZ) {
        uint4 hv = *(const uint4*)(hidden_in + (size_t)src * HD + hc8);
        v0.x += bflo(hv.x); v0.y += bfhi(hv.x);
        v0.z += bflo(hv.y); v0.w += bfhi(hv.y);
        v1.x += bflo(hv.z); v1.y += bfhi(hv.z);
        v1.z += bflo(hv.w); v1.w += bfhi(hv.w);
    }
    float sA = (cl == 0) ? sc : 0.f;
    float sB = (cl == 1) ? sc : 0.f;
    float sC = (cl == 2) ? sc : 0.f;
    A[0].x = fmaf(sA, v0.x, A[0].x); A[0].y = fmaf(sA, v0.y, A[0].y);
    A[0].z = fmaf(sA, v0.z, A[0].z); A[0].w = fmaf(sA, v0.w, A[0].w);
    A[1].x = fmaf(sA, v1.x, A[1].x); A[1].y = fmaf(sA, v1.y, A[1].y);
    A[1].z = fmaf(sA, v1.z, A[1].z); A[1].w = fmaf(sA, v1.w, A[1].w);
    A[2].x = fmaf(sB, v0.x, A[2].x); A[2].y = fmaf(sB, v0.y, A[2].y);
    A[2].z = fmaf(sB, v0.z, A[2].z); A[2].w = fmaf(sB, v0.w, A[2].w);
    A[3].x = fmaf(sB, v1.x, A[3].x); A[3].y = fmaf(sB, v1.y, A[3].y);
    A[3].z = fmaf(sB, v1.z, A[3].z); A[3].w = fmaf(sB, v1.w, A[3].w);
    A[4].x = fmaf(sC, v0.x, A[4].x); A[4].y = fmaf(sC, v0.y, A[4].y);
    A[4].z = fmaf(sC, v0.z, A[4].z); A[4].w = fmaf(sC, v0.w, A[4].w);
    A[5].x = fmaf(sC, v1.x, A[5].x); A[5].y = fmaf(sC, v1.y, A[5].y);
    A[5].z = fmaf(sC, v1.z, A[5].z); A[5].w = fmaf(sC, v1.w, A[5].w);
}

// ---------------------------------------------------------------------------
// Fused segmented-reduce + transform + next-layer proj epilogue.
// Degree-balanced: block handles nodes perm[node0..node0+63] (perm sorted by
// descending degree) so the 8 groups of a wave get near-equal segment
// lengths (kills exec-mask divergence waste; R9 lesson) and heavy blocks
// launch first. 8-lane groups: 8 edges in flight per wave, x2 unroll.
#define LPITCH 65
template <bool HZ, bool PROJ>
__global__ __launch_bounds__(256, 4) void reduce_transform_kernel(
    const ushort* __restrict__ hidden_in,   // bf16 [NN][64]
    const float* __restrict__ rela,         // layer slice [231][64] fp32
    const float* __restrict__ temb,         // [365][64] fp32
    const float* __restrict__ score,        // [E] sorted
    const int2* __restrict__ meta,          // [E] sorted
    const int*  __restrict__ off,           // [NN+1]
    const int*  __restrict__ perm,          // [NN] desc-degree node order
    const float* __restrict__ WT,           // [192][64]
    const float* __restrict__ W1next,       // next layer slice [5][192] (if PROJ)
    ushort* __restrict__ hidden_out,        // bf16 [NN][64]
    float* __restrict__ proj_out)           // [NN][8] (if PROJ)
{
    __shared__ float lds_t[64 * LPITCH];
    int tid  = threadIdx.x;
    int lane = tid & 63;
    int w    = __builtin_amdgcn_readfirstlane(tid >> 6);  // 0..3
    int g    = lane >> 3;                                  // 0..7
    int hc   = lane & 7;                                   // 0..7
    int hc8  = hc * 8;
    int node0 = blockIdx.x * 64;
    int h0 = w * 16;

    float4 a[2][6];
    #pragma unroll
    for (int rr = 0; rr < 2; ++rr)
        #pragma unroll
        for (int c = 0; c < 6; ++c)
            a[rr][c] = make_float4(0.f, 0.f, 0.f, 0.f);

    #pragma unroll
    for (int rr = 0; rr < 2; ++rr) {
        int pidx = node0 + w * 16 + rr * 8 + g;
        if (pidx >= NN) continue;
        int node = perm[pidx];
        int o0 = off[node];
        int o1 = off[node + 1];
        int j = o0;
        for (; j + 2 <= o1; j += 2) {
            int2 m0 = meta[j], m1 = meta[j + 1];
            float s0 = score[j], s1 = score[j + 1];
            edge1<HZ>(m0, s0, hc8, hidden_in, rela, temb, a[rr]);
            edge1<HZ>(m1, s1, hc8, hidden_in, rela, temb, a[rr]);
        }
        if (j < o1)
            edge1<HZ>(meta[j], score[j], hc8, hidden_in, rela, temb, a[rr]);
    }

    // --- transform, one class slab at a time ---
    float acc[16];
    #pragma unroll
    for (int i = 0; i < 16; ++i) acc[i] = 0.f;

    #pragma unroll
    for (int c = 0; c < 3; ++c) {
        __syncthreads();   // protect previous slab's reads
        #pragma unroll
        for (int rr = 0; rr < 2; ++rr) {
            int nl = w * 16 + rr * 8 + g;
            float4 lo = a[rr][2 * c];
            float4 hi = a[rr][2 * c + 1];
            lds_t[(hc8 + 0) * LPITCH + nl] = lo.x;
            lds_t[(hc8 + 1) * LPITCH + nl] = lo.y;
            lds_t[(hc8 + 2) * LPITCH + nl] = lo.z;
            lds_t[(hc8 + 3) * LPITCH + nl] = lo.w;
            lds_t[(hc8 + 4) * LPITCH + nl] = hi.x;
            lds_t[(hc8 + 5) * LPITCH + nl] = hi.y;
            lds_t[(hc8 + 6) * LPITCH + nl] = hi.z;
            lds_t[(hc8 + 7) * LPITCH + nl] = hi.w;
        }
        __syncthreads();
        const float* __restrict__ Wb = WT + (c * 64) * 64 + h0;
        #pragma unroll 4
        for (int k = 0; k < 64; ++k) {
            float av = lds_t[k * LPITCH + lane];
            #pragma unroll
            for (int i = 0; i < 16; ++i)
                acc[i] = fmaf(av, Wb[k * 64 + i], acc[i]);
        }
    }

    int pl = node0 + lane;
    if (pl < NN) {
        int node = perm[pl];
        ushort* outp = hidden_out + (size_t)node * 64 + h0;
        unsigned up[8];
        #pragma unroll
        for (int p = 0; p < 8; ++p)
            up[p] = packbf2(fmaxf(acc[2 * p], 0.f), fmaxf(acc[2 * p + 1], 0.f));
        *(uint4*)(outp)     = make_uint4(up[0], up[1], up[2], up[3]);
        *(uint4*)(outp + 8) = make_uint4(up[4], up[5], up[6], up[7]);
    }

    // --- epilogue: proj for NEXT layer from fp32 acc (exact) ---
    if (PROJ) {
        float pa[AD];
        #pragma unroll
        for (int aa = 0; aa < AD; ++aa) pa[aa] = 0.f;
        #pragma unroll
        for (int i = 0; i < 16; ++i) {
            float hv = fmaxf(acc[i], 0.f);
            #pragma unroll
            for (int aa = 0; aa < AD; ++aa)
                pa[aa] = fmaf(hv, W1next[aa * 192 + h0 + i], pa[aa]);
        }
        __syncthreads();
        float* lds2 = lds_t;   // reuse as [4][64][5]
        #pragma unroll
        for (int aa = 0; aa < AD; ++aa)
            lds2[(w * 64 + lane) * AD + aa] = pa[aa];
        __syncthreads();
        for (int idx = tid; idx < 64 * 8; idx += 256) {
            int nd = idx >> 3, aa = idx & 7;
            if (node0 + nd >= NN) break;
            float v = 0.f;
            if (aa < AD) {
                #pragma unroll
                for (int w4 = 0; w4 < 4; ++w4)
                    v += lds2[(w4 * 64 + nd) * AD + aa];
            }
            proj_out[(size_t)perm[node0 + nd] * 8 + aa] = v;
        }
    }
}

// ---------------------------------------------------------------------------
__global__ __launch_bounds__(256) void out_kernel(
    const ushort* __restrict__ hidden,   // bf16 [NN][64]
    const float* __restrict__ Wc,
    const float* __restrict__ bc,
    float* __restrict__ out)
{
    int i = blockIdx.x * 256 + threadIdx.x;
    if (i >= NOUT) return;
    float r = 0.f;
    if (i < NN) {
        const uint4* h4 = (const uint4*)(hidden + (size_t)i * 64);
        float acc = 0.f;
        #pragma unroll
        for (int q = 0; q < 8; ++q) {
            uint4 hv = h4[q];
            const float* wq = Wc + q * 8;
            acc = fmaf(bflo(hv.x), wq[0], acc);
            acc = fmaf(bfhi(hv.x), wq[1], acc);
            acc = fmaf(bflo(hv.y), wq[2], acc);
            acc = fmaf(bfhi(hv.y), wq[3], acc);
            acc = fmaf(bflo(hv.z), wq[4], acc);
            acc = fmaf(bfhi(hv.z), wq[5], acc);
            acc = fmaf(bflo(hv.w), wq[6], acc);
            acc = fmaf(bfhi(hv.w), wq[7], acc);
        }
        r = acc + bc[0];
    }
    out[i] = r;
}

// ---------------------------------------------------------------------------
extern "C" void kernel_launch(void* const* d_in, const int* in_sizes, int n_in,
                              void* d_out, int out_size, void* d_ws, size_t ws_size,
                              hipStream_t stream)
{
    const int*   batch_idx  = (const int*)d_in[0];
    const int*   src_idx    = (const int*)d_in[1];
    const int*   dst_idx    = (const int*)d_in[2];
    const int*   rel_idx    = (const int*)d_in[3];
    const int*   rel_time   = (const int*)d_in[4];
    const int*   query_rel  = (const int*)d_in[5];
    const float* rela_embed = (const float*)d_in[8];   // [3][231][64]
    const float* time_embed = (const float*)d_in[9];   // [365][64]
    const float* Wp         = (const float*)d_in[10];
    const float* Wn         = (const float*)d_in[11];
    const float* Wf         = (const float*)d_in[12];
    const float* W1         = (const float*)d_in[13];  // [3][5][192]
    const float* W2         = (const float*)d_in[14];  // [3][1][5]
    const float* Wc         = (const float*)d_in[15];  // [64]
    const float* bc         = (const float*)d_in[16];  // [1]
    float* out = (float*)d_out;

    char* ws = (char*)d_ws;
    ushort* hid0  = (ushort*)(ws + 0);           // 12.8 MB bf16
    ushort* hid1  = (ushort*)(ws + 12800000);    // 12.8 MB bf16
    float* projA  = (float*)(ws + 25600000);     //  3.2 MB
    float* projB  = (float*)(ws + 28800000);     //  3.2 MB
    float* score  = (float*)(ws + 32000000);     //  4.0 MB
    float* WT     = (float*)(ws + 36000000);     //  48 KB
    float* Trel   = (float*)(ws + 36100000);     //  ~22 KB
    float* Tq     = (float*)(ws + 36130000);     //  ~22 KB
    int*   off    = (int*)  (ws + 36160000);     // 400 KB (NN+1)
    int2*  meta   = (int2*) (ws + 37400000);     //  8.0 MB
    int*   deg    = (int*)  (ws + 45400000);     // 400 KB
    int*   tmp    = (int*)  (ws + 46600000);     // 400 KB
    int*   cursor = (int*)  (ws + 47800000);     // 400 KB
    int*   bsum   = (int*)  (ws + 49000000);     //  ~2 KB
    int*   bpref  = (int*)  (ws + 49010000);     //  ~2 KB
    int*   dhist  = (int*)  (ws + 49020000);     //   4 KB
    int*   dcur   = (int*)  (ws + 49030000);     //   4 KB
    int*   perm   = (int*)  (ws + 49040000);     // 400 KB

    prep_wt_kernel<<<48, 256, 0, stream>>>(Wp, Wn, Wf, WT);
    prep_tables_kernel<<<NL, 256, 0, stream>>>(rela_embed, W1, Trel, Tq);

    // --- counting sort by dst; layer-0 score computed in scatter ---
    hipMemsetAsync(deg, 0, NN * sizeof(int), stream);
    hipMemsetAsync(dhist, 0, NDBIN * sizeof(int), stream);
    hist_kernel<<<(NE + 255) / 256, 256, 0, stream>>>(dst_idx, deg);
    scan1_kernel<<<NBLK1, 256, 0, stream>>>(deg, tmp, bsum);
    scan2_kernel<<<1, 512, 0, stream>>>(bsum, bpref);
    scan3_kernel<<<NBLK1, 256, 0, stream>>>(deg, tmp, bpref, off, cursor, dhist);
    dscan_kernel<<<1, NDBIN, 0, stream>>>(dhist, dcur);
    dscatter_kernel<<<NBLK1, 256, 0, stream>>>(deg, dcur, perm);
    sort_scatter_kernel<<<(NE + 255) / 256, 256, 0, stream>>>(
        dst_idx, src_idx, rel_idx, rel_time, batch_idx, query_rel,
        Trel, Tq, W2, cursor, meta, score);

    // --- layers: L0 -> hid0/projA ; L1 hid0,projA -> hid1/projB ;
    //             L2 hid1,projB -> hid0 ---
    int grid = (NN + 63) / 64;
    int sgrid = (NE + 255) / 256;
    {
        reduce_transform_kernel<true, true><<<grid, 256, 0, stream>>>(
            hid1, rela_embed, time_embed, score, meta, off, perm,
            WT, W1 + (size_t)1 * AD * 192, hid0, projA);
    }
    {
        const float* rela = rela_embed + (size_t)1 * NRL * HD;
        score_kernel<<<sgrid, 256, 0, stream>>>(
            projA, Trel + (size_t)1 * NRL * 8, Tq + (size_t)1 * NRL * 8,
            W2 + 1 * AD, meta, score);
        reduce_transform_kernel<false, true><<<grid, 256, 0, stream>>>(
            hid0, rela, time_embed, score, meta, off, perm,
            WT, W1 + (size_t)2 * AD * 192, hid1, projB);
    }
    {
        const float* rela = rela_embed + (size_t)2 * NRL * HD;
        score_kernel<<<sgrid, 256, 0, stream>>>(
            projB, Trel + (size_t)2 * NRL * 8, Tq + (size_t)2 * NRL * 8,
            W2 + 2 * AD, meta, score);
        reduce_transform_kernel<false, false><<<grid, 256, 0, stream>>>(
            hid1, rela, time_embed, score, meta, off, perm,
            WT, nullptr, hid0, nullptr);
    }

    out_kernel<<<(NOUT + 255) / 256, 256, 0, stream>>>(hid0, Wc, bc, out);
}

// Round 11
// 489.380 us; speedup vs baseline: 2.2078x; 2.2078x over previous
//
#include <hip/hip_runtime.h>

#define NB   32
#define NN   100000
#define NE   1000000
#define HD   64
#define AD   5
#define NL   3
#define NRL  231      // N_REL + 1
#define NTM  365
#define NOUT 228096   // 32 * 7128
#define NBLK1 391     // ceil(NN/256)
#define NDBIN 1024    // degree bins for balance sort
#define BHP  392      // blockhist pitch (NBLK1+1)

// meta packing: w0 = src | (rel<<17) | (cls<<25) ; w1 = ta | (q<<9)

// bf16 helpers
__device__ __forceinline__ float bflo(unsigned u) { return __uint_as_float(u << 16); }
__device__ __forceinline__ float bfhi(unsigned u) { return __uint_as_float(u & 0xffff0000u); }
__device__ __forceinline__ unsigned packbf2(float x, float y) {
    unsigned ux = __float_as_uint(x), uy = __float_as_uint(y);
    ux = (ux + 0x7fffu + ((ux >> 16) & 1u)) >> 16;
    uy = (uy + 0x7fffu + ((uy >> 16) & 1u)) >> 16;
    return ux | (uy << 16);
}

// ---------------------------------------------------------------------------
__global__ __launch_bounds__(256) void prep_wt_kernel(
    const float* __restrict__ Wp, const float* __restrict__ Wn,
    const float* __restrict__ Wf, float* __restrict__ WT)
{
    int i = blockIdx.x * 256 + threadIdx.x;
    if (i >= 3 * 64 * 64) return;
    int c = i >> 12;
    int k = (i >> 6) & 63;
    int h = i & 63;
    const float* W = (c == 0) ? Wf : (c == 1 ? Wn : Wp);
    WT[i] = W[h * 64 + k];
}

// ---------------------------------------------------------------------------
__global__ __launch_bounds__(256) void prep_tables_kernel(
    const float* __restrict__ rela_embed,   // [3][231][64]
    const float* __restrict__ W1,           // [3][5][192]
    float* __restrict__ Trel,               // [3][231][8]
    float* __restrict__ Tq)                 // [3][231][8]
{
    int l = blockIdx.x;
    int r = threadIdx.x;
    if (r >= NRL) return;
    const float4* rrow = (const float4*)(rela_embed + ((size_t)l * NRL + r) * HD);
    const float* W1l = W1 + (size_t)l * AD * 192;
    float tr[AD] = {0,0,0,0,0}, tq[AD] = {0,0,0,0,0};
    #pragma unroll
    for (int k4 = 0; k4 < 16; ++k4) {
        float4 x = rrow[k4];
        #pragma unroll
        for (int a = 0; a < AD; ++a) {
            const float* wr = W1l + a * 192 + 64 + k4 * 4;
            const float* wq = W1l + a * 192 + 128 + k4 * 4;
            tr[a] = fmaf(x.x, wr[0], tr[a]); tr[a] = fmaf(x.y, wr[1], tr[a]);
            tr[a] = fmaf(x.z, wr[2], tr[a]); tr[a] = fmaf(x.w, wr[3], tr[a]);
            tq[a] = fmaf(x.x, wq[0], tq[a]); tq[a] = fmaf(x.y, wq[1], tq[a]);
            tq[a] = fmaf(x.z, wq[2], tq[a]); tq[a] = fmaf(x.w, wq[3], tq[a]);
        }
    }
    float* tro = Trel + ((size_t)l * NRL + r) * 8;
    float* tqo = Tq   + ((size_t)l * NRL + r) * 8;
    #pragma unroll
    for (int a = 0; a < AD; ++a) { tro[a] = tr[a]; tqo[a] = tq[a]; }
    tro[5] = tro[6] = tro[7] = 0.f;
    tqo[5] = tqo[6] = tqo[7] = 0.f;
}

// ---------------------------------------------------------------------------
// Counting sort by dst
__global__ __launch_bounds__(256) void hist_kernel(
    const int* __restrict__ dst_idx, int* __restrict__ deg)
{
    int e = blockIdx.x * 256 + threadIdx.x;
    if (e < NE) atomicAdd(&deg[dst_idx[e]], 1);
}

__global__ __launch_bounds__(256) void scan1_kernel(
    const int* __restrict__ deg, int* __restrict__ tmp, int* __restrict__ bsum)
{
    __shared__ int s[256];
    int tid = threadIdx.x;
    int i = blockIdx.x * 256 + tid;
    int v = (i < NN) ? deg[i] : 0;
    s[tid] = v;
    __syncthreads();
    #pragma unroll
    for (int st = 1; st < 256; st <<= 1) {
        int t = (tid >= st) ? s[tid - st] : 0;
        __syncthreads();
        s[tid] += t;
        __syncthreads();
    }
    if (i < NN) tmp[i] = s[tid];
    if (tid == 255) bsum[blockIdx.x] = s[255];
}

__global__ __launch_bounds__(512) void scan2_kernel(
    const int* __restrict__ bsum, int* __restrict__ bpref)
{
    __shared__ int s[512];
    int tid = threadIdx.x;
    int v = (tid < NBLK1) ? bsum[tid] : 0;
    s[tid] = v;
    __syncthreads();
    #pragma unroll
    for (int st = 1; st < 512; st <<= 1) {
        int t = (tid >= st) ? s[tid - st] : 0;
        __syncthreads();
        s[tid] += t;
        __syncthreads();
    }
    if (tid < NBLK1) bpref[tid] = s[tid] - v;  // exclusive
}

__global__ __launch_bounds__(256) void scan3_kernel(
    const int* __restrict__ deg, const int* __restrict__ tmp,
    const int* __restrict__ bpref, int* __restrict__ off, int* __restrict__ cursor)
{
    int i = blockIdx.x * 256 + threadIdx.x;
    if (i >= NN) return;
    int d = deg[i];
    int incl = tmp[i] + bpref[i >> 8];
    off[i + 1] = incl;
    cursor[i] = incl - d;
    if (i == 0) off[0] = 0;
}

// ---------------------------------------------------------------------------
// Degree-balance sort (contention-free; R10 lesson: same-address global
// atomics serialize — use LDS histograms + scans instead).
// 1) per-block LDS degree-bin histogram -> blockhist[bin][blk]
__global__ __launch_bounds__(256) void bhist_kernel(
    const int* __restrict__ deg, int* __restrict__ blockhist)
{
    __shared__ int h[NDBIN];
    int tid = threadIdx.x;
    #pragma unroll
    for (int b = tid; b < NDBIN; b += 256) h[b] = 0;
    __syncthreads();
    int n = blockIdx.x * 256 + tid;
    if (n < NN) {
        int d = deg[n];
        int bin = (d < NDBIN) ? d : (NDBIN - 1);
        atomicAdd(&h[bin], 1);
    }
    __syncthreads();
    #pragma unroll
    for (int b = tid; b < NDBIN; b += 256)
        blockhist[b * BHP + blockIdx.x] = h[b];
}

// 2) per-bin exclusive scan over blocks (contiguous row) + bin totals
__global__ __launch_bounds__(256) void bscan_kernel(
    int* __restrict__ blockhist, int* __restrict__ btotal)
{
    int bin = blockIdx.x * 256 + threadIdx.x;
    if (bin >= NDBIN) return;
    int* row = blockhist + bin * BHP;
    int cum = 0;
    for (int b = 0; b < NBLK1; ++b) {
        int v = row[b];
        row[b] = cum;       // exclusive
        cum += v;
    }
    btotal[bin] = cum;
}

// 3) descending-degree bin starts: dstart[bin] = total_all - incl_prefix(bin)
__global__ __launch_bounds__(1024) void dstart_kernel(
    const int* __restrict__ btotal, int* __restrict__ dstart)
{
    __shared__ int s[NDBIN];
    int tid = threadIdx.x;
    int v = btotal[tid];
    s[tid] = v;
    __syncthreads();
    #pragma unroll
    for (int st = 1; st < NDBIN; st <<= 1) {
        int t = (tid >= st) ? s[tid - st] : 0;
        __syncthreads();
        s[tid] += t;
        __syncthreads();
    }
    dstart[tid] = s[NDBIN - 1] - s[tid];
}

// 4) scatter: pos = dstart[bin] + blockpref[bin][blk] + LDS-local rank
__global__ __launch_bounds__(256) void dscatter2_kernel(
    const int* __restrict__ deg, const int* __restrict__ blockhist,
    const int* __restrict__ dstart, int* __restrict__ perm)
{
    __shared__ int h[NDBIN];
    int tid = threadIdx.x;
    #pragma unroll
    for (int b = tid; b < NDBIN; b += 256) h[b] = 0;
    __syncthreads();
    int n = blockIdx.x * 256 + tid;
    if (n < NN) {
        int d = deg[n];
        int bin = (d < NDBIN) ? d : (NDBIN - 1);
        int r = atomicAdd(&h[bin], 1);          // LDS atomic: cheap
        int pos = dstart[bin] + blockhist[bin * BHP + blockIdx.x] + r;
        perm[pos] = n;
    }
}

// ---------------------------------------------------------------------------
// scatter into dst-sorted order; also computes layer-0 score
__global__ __launch_bounds__(256) void sort_scatter_kernel(
    const int* __restrict__ dst_idx, const int* __restrict__ src_idx,
    const int* __restrict__ rel_idx, const int* __restrict__ rel_time,
    const int* __restrict__ batch_idx, const int* __restrict__ query_rel,
    const float* __restrict__ Trel0, const float* __restrict__ Tq0,
    const float* __restrict__ W2,
    int* __restrict__ cursor, int2* __restrict__ meta,
    float* __restrict__ score0)
{
    int e = blockIdx.x * 256 + threadIdx.x;
    if (e >= NE) return;
    int d = dst_idx[e];
    int rt = rel_time[e];
    int cls = (rt > 0) ? 0 : ((rt == 0) ? 1 : 2);
    int ta = (rt < 0) ? -rt : rt;
    int rel = rel_idx[e];
    int q = query_rel[batch_idx[e]];
    int pos = atomicAdd(&cursor[d], 1);
    int2 m;
    m.x = src_idx[e] | (rel << 17) | (cls << 25);
    m.y = ta | (q << 9);
    meta[pos] = m;

    float4 t0 = *(const float4*)(Trel0 + rel * 8);
    float  t4 = Trel0[rel * 8 + 4];
    float4 u0 = *(const float4*)(Tq0 + q * 8);
    float  u4 = Tq0[q * 8 + 4];
    float z = 0.f;
    z = fmaf(fmaxf(t0.x + u0.x, 0.f), W2[0], z);
    z = fmaf(fmaxf(t0.y + u0.y, 0.f), W2[1], z);
    z = fmaf(fmaxf(t0.z + u0.z, 0.f), W2[2], z);
    z = fmaf(fmaxf(t0.w + u0.w, 0.f), W2[3], z);
    z = fmaf(fmaxf(t4   + u4,   0.f), W2[4], z);
    score0[pos] = 1.f / (1.f + __expf(-z));
}

// ---------------------------------------------------------------------------
// Standalone score for L1/L2 (64 edges/wave — R6 lesson).
__global__ __launch_bounds__(256) void score_kernel(
    const float* __restrict__ proj,     // [NN][8]
    const float* __restrict__ Trel,
    const float* __restrict__ Tq,
    const float* __restrict__ W2,
    const int2* __restrict__ meta,
    float* __restrict__ score)
{
    int j = blockIdx.x * 256 + threadIdx.x;
    if (j >= NE) return;
    int2 mt = meta[j];
    int rel = (mt.x >> 17) & 0xFF;
    int q   = (mt.y >> 9) & 0xFF;
    int src = mt.x & 0x1FFFF;

    float4 t0 = *(const float4*)(Trel + rel * 8);
    float  t4 = Trel[rel * 8 + 4];
    float4 u0 = *(const float4*)(Tq + q * 8);
    float  u4 = Tq[q * 8 + 4];
    float4 p0 = *(const float4*)(proj + (size_t)src * 8);
    float  p4 = proj[(size_t)src * 8 + 4];
    float z = 0.f;
    z = fmaf(fmaxf(p0.x + t0.x + u0.x, 0.f), W2[0], z);
    z = fmaf(fmaxf(p0.y + t0.y + u0.y, 0.f), W2[1], z);
    z = fmaf(fmaxf(p0.z + t0.z + u0.z, 0.f), W2[2], z);
    z = fmaf(fmaxf(p0.w + t0.w + u0.w, 0.f), W2[3], z);
    z = fmaf(fmaxf(p4   + t4   + u4,   0.f), W2[4], z);
    score[j] = 1.f / (1.f + __expf(-z));
}

// ---------------------------------------------------------------------------
// One edge, 8-lane group (lane covers h = hc*8..hc*8+7).
template <bool HZ>
__device__ __forceinline__ void edge1(
    int2 m, float sc, int hc8,
    const ushort* __restrict__ hidden_in,
    const float* __restrict__ rela, const float* __restrict__ temb,
    float4* __restrict__ A)
{
    int src = m.x & 0x1FFFF, rel = (m.x >> 17) & 0xFF;
    int cl  = (m.x >> 25) & 3, ta = m.y & 511;
    const float* rp = rela + rel * HD + hc8;
    const float* tp = temb + ta * HD + hc8;
    float4 rv0 = *(const float4*)rp;
    float4 rv1 = *(const float4*)(rp + 4);
    float4 tv0 = *(const float4*)tp;
    float4 tv1 = *(const float4*)(tp + 4);
    float4 v0, v1;
    v0.x = rv0.x + tv0.x; v0.y = rv0.y + tv0.y;
    v0.z = rv0.z + tv0.z; v0.w = rv0.w + tv0.w;
    v1.x = rv1.x + tv1.x; v1.y = rv1.y + tv1.y;
    v1.z = rv1.z + tv1.z; v1.w = rv1.w + tv1.w;
    if (!HZ) {
        uint4 hv = *(const uint4*)(hidden_in + (size_t)src * HD + hc8);
        v0.x += bflo(hv.x); v0.y += bfhi(hv.x);
        v0.z += bflo(hv.y); v0.w += bfhi(hv.y);
        v1.x += bflo(hv.z); v1.y += bfhi(hv.z);
        v1.z += bflo(hv.w); v1.w += bfhi(hv.w);
    }
    float sA = (cl == 0) ? sc : 0.f;
    float sB = (cl == 1) ? sc : 0.f;
    float sC = (cl == 2) ? sc : 0.f;
    A[0].x = fmaf(sA, v0.x, A[0].x); A[0].y = fmaf(sA, v0.y, A[0].y);
    A[0].z = fmaf(sA, v0.z, A[0].z); A[0].w = fmaf(sA, v0.w, A[0].w);
    A[1].x = fmaf(sA, v1.x, A[1].x); A[1].y = fmaf(sA, v1.y, A[1].y);
    A[1].z = fmaf(sA, v1.z, A[1].z); A[1].w = fmaf(sA, v1.w, A[1].w);
    A[2].x = fmaf(sB, v0.x, A[2].x); A[2].y = fmaf(sB, v0.y, A[2].y);
    A[2].z = fmaf(sB, v0.z, A[2].z); A[2].w = fmaf(sB, v0.w, A[2].w);
    A[3].x = fmaf(sB, v1.x, A[3].x); A[3].y = fmaf(sB, v1.y, A[3].y);
    A[3].z = fmaf(sB, v1.z, A[3].z); A[3].w = fmaf(sB, v1.w, A[3].w);
    A[4].x = fmaf(sC, v0.x, A[4].x); A[4].y = fmaf(sC, v0.y, A[4].y);
    A[4].z = fmaf(sC, v0.z, A[4].z); A[4].w = fmaf(sC, v0.w, A[4].w);
    A[5].x = fmaf(sC, v1.x, A[5].x); A[5].y = fmaf(sC, v1.y, A[5].y);
    A[5].z = fmaf(sC, v1.z, A[5].z); A[5].w = fmaf(sC, v1.w, A[5].w);
}

// ---------------------------------------------------------------------------
// Fused segmented-reduce + transform + next-layer proj epilogue.
// Degree-balanced via perm (desc degree). 8-lane groups, x2 unroll.
#define LPITCH 65
template <bool HZ, bool PROJ>
__global__ __launch_bounds__(256, 4) void reduce_transform_kernel(
    const ushort* __restrict__ hidden_in,   // bf16 [NN][64]
    const float* __restrict__ rela,         // layer slice [231][64] fp32
    const float* __restrict__ temb,         // [365][64] fp32
    const float* __restrict__ score,        // [E] sorted
    const int2* __restrict__ meta,          // [E] sorted
    const int*  __restrict__ off,           // [NN+1]
    const int*  __restrict__ perm,          // [NN] desc-degree node order
    const float* __restrict__ WT,           // [192][64]
    const float* __restrict__ W1next,       // next layer slice [5][192] (if PROJ)
    ushort* __restrict__ hidden_out,        // bf16 [NN][64]
    float* __restrict__ proj_out)           // [NN][8] (if PROJ)
{
    __shared__ float lds_t[64 * LPITCH];
    int tid  = threadIdx.x;
    int lane = tid & 63;
    int w    = __builtin_amdgcn_readfirstlane(tid >> 6);  // 0..3
    int g    = lane >> 3;                                  // 0..7
    int hc   = lane & 7;                                   // 0..7
    int hc8  = hc * 8;
    int node0 = blockIdx.x * 64;
    int h0 = w * 16;

    float4 a[2][6];
    #pragma unroll
    for (int rr = 0; rr < 2; ++rr)
        #pragma unroll
        for (int c = 0; c < 6; ++c)
            a[rr][c] = make_float4(0.f, 0.f, 0.f, 0.f);

    #pragma unroll
    for (int rr = 0; rr < 2; ++rr) {
        int pidx = node0 + w * 16 + rr * 8 + g;
        if (pidx >= NN) continue;
        int node = perm[pidx];
        int o0 = off[node];
        int o1 = off[node + 1];
        int j = o0;
        for (; j + 2 <= o1; j += 2) {
            int2 m0 = meta[j], m1 = meta[j + 1];
            float s0 = score[j], s1 = score[j + 1];
            edge1<HZ>(m0, s0, hc8, hidden_in, rela, temb, a[rr]);
            edge1<HZ>(m1, s1, hc8, hidden_in, rela, temb, a[rr]);
        }
        if (j < o1)
            edge1<HZ>(meta[j], score[j], hc8, hidden_in, rela, temb, a[rr]);
    }

    // --- transform, one class slab at a time ---
    float acc[16];
    #pragma unroll
    for (int i = 0; i < 16; ++i) acc[i] = 0.f;

    #pragma unroll
    for (int c = 0; c < 3; ++c) {
        __syncthreads();
        #pragma unroll
        for (int rr = 0; rr < 2; ++rr) {
            int nl = w * 16 + rr * 8 + g;
            float4 lo = a[rr][2 * c];
            float4 hi = a[rr][2 * c + 1];
            lds_t[(hc8 + 0) * LPITCH + nl] = lo.x;
            lds_t[(hc8 + 1) * LPITCH + nl] = lo.y;
            lds_t[(hc8 + 2) * LPITCH + nl] = lo.z;
            lds_t[(hc8 + 3) * LPITCH + nl] = lo.w;
            lds_t[(hc8 + 4) * LPITCH + nl] = hi.x;
            lds_t[(hc8 + 5) * LPITCH + nl] = hi.y;
            lds_t[(hc8 + 6) * LPITCH + nl] = hi.z;
            lds_t[(hc8 + 7) * LPITCH + nl] = hi.w;
        }
        __syncthreads();
        const float* __restrict__ Wb = WT + (c * 64) * 64 + h0;
        #pragma unroll 4
        for (int k = 0; k < 64; ++k) {
            float av = lds_t[k * LPITCH + lane];
            #pragma unroll
            for (int i = 0; i < 16; ++i)
                acc[i] = fmaf(av, Wb[k * 64 + i], acc[i]);
        }
    }

    int pl = node0 + lane;
    if (pl < NN) {
        int node = perm[pl];
        ushort* outp = hidden_out + (size_t)node * 64 + h0;
        unsigned up[8];
        #pragma unroll
        for (int p = 0; p < 8; ++p)
            up[p] = packbf2(fmaxf(acc[2 * p], 0.f), fmaxf(acc[2 * p + 1], 0.f));
        *(uint4*)(outp)     = make_uint4(up[0], up[1], up[2], up[3]);
        *(uint4*)(outp + 8) = make_uint4(up[4], up[5], up[6], up[7]);
    }

    // --- epilogue: proj for NEXT layer from fp32 acc (exact) ---
    if (PROJ) {
        float pa[AD];
        #pragma unroll
        for (int aa = 0; aa < AD; ++aa) pa[aa] = 0.f;
        #pragma unroll
        for (int i = 0; i < 16; ++i) {
            float hv = fmaxf(acc[i], 0.f);
            #pragma unroll
            for (int aa = 0; aa < AD; ++aa)
                pa[aa] = fmaf(hv, W1next[aa * 192 + h0 + i], pa[aa]);
        }
        __syncthreads();
        float* lds2 = lds_t;   // reuse as [4][64][5]
        #pragma unroll
        for (int aa = 0; aa < AD; ++aa)
            lds2[(w * 64 + lane) * AD + aa] = pa[aa];
        __syncthreads();
        for (int idx = tid; idx < 64 * 8; idx += 256) {
            int nd = idx >> 3, aa = idx & 7;
            if (node0 + nd >= NN) break;
            float v = 0.f;
            if (aa < AD) {
                #pragma unroll
                for (int w4 = 0; w4 < 4; ++w4)
                    v += lds2[(w4 * 64 + nd) * AD + aa];
            }
            proj_out[(size_t)perm[node0 + nd] * 8 + aa] = v;
        }
    }
}

// ---------------------------------------------------------------------------
__global__ __launch_bounds__(256) void out_kernel(
    const ushort* __restrict__ hidden,   // bf16 [NN][64]
    const float* __restrict__ Wc,
    const float* __restrict__ bc,
    float* __restrict__ out)
{
    int i = blockIdx.x * 256 + threadIdx.x;
    if (i >= NOUT) return;
    float r = 0.f;
    if (i < NN) {
        const uint4* h4 = (const uint4*)(hidden + (size_t)i * 64);
        float acc = 0.f;
        #pragma unroll
        for (int q = 0; q < 8; ++q) {
            uint4 hv = h4[q];
            const float* wq = Wc + q * 8;
            acc = fmaf(bflo(hv.x), wq[0], acc);
            acc = fmaf(bfhi(hv.x), wq[1], acc);
            acc = fmaf(bflo(hv.y), wq[2], acc);
            acc = fmaf(bfhi(hv.y), wq[3], acc);
            acc = fmaf(bflo(hv.z), wq[4], acc);
            acc = fmaf(bfhi(hv.z), wq[5], acc);
            acc = fmaf(bflo(hv.w), wq[6], acc);
            acc = fmaf(bfhi(hv.w), wq[7], acc);
        }
        r = acc + bc[0];
    }
    out[i] = r;
}

// ---------------------------------------------------------------------------
extern "C" void kernel_launch(void* const* d_in, const int* in_sizes, int n_in,
                              void* d_out, int out_size, void* d_ws, size_t ws_size,
                              hipStream_t stream)
{
    const int*   batch_idx  = (const int*)d_in[0];
    const int*   src_idx    = (const int*)d_in[1];
    const int*   dst_idx    = (const int*)d_in[2];
    const int*   rel_idx    = (const int*)d_in[3];
    const int*   rel_time   = (const int*)d_in[4];
    const int*   query_rel  = (const int*)d_in[5];
    const float* rela_embed = (const float*)d_in[8];   // [3][231][64]
    const float* time_embed = (const float*)d_in[9];   // [365][64]
    const float* Wp         = (const float*)d_in[10];
    const float* Wn         = (const float*)d_in[11];
    const float* Wf         = (const float*)d_in[12];
    const float* W1         = (const float*)d_in[13];  // [3][5][192]
    const float* W2         = (const float*)d_in[14];  // [3][1][5]
    const float* Wc         = (const float*)d_in[15];  // [64]
    const float* bc         = (const float*)d_in[16];  // [1]
    float* out = (float*)d_out;

    char* ws = (char*)d_ws;
    ushort* hid0  = (ushort*)(ws + 0);           // 12.8 MB bf16
    ushort* hid1  = (ushort*)(ws + 12800000);    // 12.8 MB bf16
    float* projA  = (float*)(ws + 25600000);     //  3.2 MB
    float* projB  = (float*)(ws + 28800000);     //  3.2 MB
    float* score  = (float*)(ws + 32000000);     //  4.0 MB
    float* WT     = (float*)(ws + 36000000);     //  48 KB
    float* Trel   = (float*)(ws + 36100000);     //  ~22 KB
    float* Tq     = (float*)(ws + 36130000);     //  ~22 KB
    int*   off    = (int*)  (ws + 36160000);     // 400 KB (NN+1)
    int2*  meta   = (int2*) (ws + 37400000);     //  8.0 MB
    int*   deg    = (int*)  (ws + 45400000);     // 400 KB
    int*   tmp    = (int*)  (ws + 46600000);     // 400 KB
    int*   cursor = (int*)  (ws + 47800000);     // 400 KB
    int*   bsum   = (int*)  (ws + 49000000);     //  ~2 KB
    int*   bpref  = (int*)  (ws + 49010000);     //  ~2 KB
    int*   perm   = (int*)  (ws + 49040000);     // 400 KB
    int*   blockhist = (int*)(ws + 49500000);    // 1024*392*4 = 1.606 MB
    int*   btotal = (int*)  (ws + 51200000);     //   4 KB
    int*   dstart = (int*)  (ws + 51210000);     //   4 KB

    prep_wt_kernel<<<48, 256, 0, stream>>>(Wp, Wn, Wf, WT);
    prep_tables_kernel<<<NL, 256, 0, stream>>>(rela_embed, W1, Trel, Tq);

    // --- counting sort by dst; layer-0 score computed in scatter ---
    hipMemsetAsync(deg, 0, NN * sizeof(int), stream);
    hist_kernel<<<(NE + 255) / 256, 256, 0, stream>>>(dst_idx, deg);
    scan1_kernel<<<NBLK1, 256, 0, stream>>>(deg, tmp, bsum);
    scan2_kernel<<<1, 512, 0, stream>>>(bsum, bpref);
    scan3_kernel<<<NBLK1, 256, 0, stream>>>(deg, tmp, bpref, off, cursor);

    // --- degree-balance perm (contention-free counting sort) ---
    bhist_kernel<<<NBLK1, 256, 0, stream>>>(deg, blockhist);
    bscan_kernel<<<(NDBIN + 255) / 256, 256, 0, stream>>>(blockhist, btotal);
    dstart_kernel<<<1, NDBIN, 0, stream>>>(btotal, dstart);
    dscatter2_kernel<<<NBLK1, 256, 0, stream>>>(deg, blockhist, dstart, perm);

    sort_scatter_kernel<<<(NE + 255) / 256, 256, 0, stream>>>(
        dst_idx, src_idx, rel_idx, rel_time, batch_idx, query_rel,
        Trel, Tq, W2, cursor, meta, score);

    // --- layers: L0 -> hid0/projA ; L1 hid0,projA -> hid1/projB ;
    //             L2 hid1,projB -> hid0 ---
    int grid = (NN + 63) / 64;
    int sgrid = (NE + 255) / 256;
    {
        reduce_transform_kernel<true, true><<<grid, 256, 0, stream>>>(
            hid1, rela_embed, time_embed, score, meta, off, perm,
            WT, W1 + (size_t)1 * AD * 192, hid0, projA);
    }
    {
        const float* rela = rela_embed + (size_t)1 * NRL * HD;
        score_kernel<<<sgrid, 256, 0, stream>>>(
            projA, Trel + (size_t)1 * NRL * 8, Tq + (size_t)1 * NRL * 8,
            W2 + 1 * AD, meta, score);
        reduce_transform_kernel<false, true><<<grid, 256, 0, stream>>>(
            hid0, rela, time_embed, score, meta, off, perm,
            WT, W1 + (size_t)2 * AD * 192, hid1, projB);
    }
    {
        const float* rela = rela_embed + (size_t)2 * NRL * HD;
        score_kernel<<<sgrid, 256, 0, stream>>>(
            projB, Trel + (size_t)2 * NRL * 8, Tq + (size_t)2 * NRL * 8,
            W2 + 2 * AD, meta, score);
        reduce_transform_kernel<false, false><<<grid, 256, 0, stream>>>(
            hid1, rela, time_embed, score, meta, off, perm,
            WT, nullptr, hid0, nullptr);
    }

    out_kernel<<<(NOUT + 255) / 256, 256, 0, stream>>>(hid0, Wc, bc, out);
}